// Round 11
// baseline (832.575 us; speedup 1.0000x reference)
//
#include <hip/hip_runtime.h>
#include <math.h>

// HyperbolicGraphConvolution on MI355X.
// N=100000, D=65 (col 0 identically 0 through GCN hops -> propagate 64), E=1.6M.
// r8 profile: k_spmm FETCH 197MB/dispatch ~= 8 XCDs x 25.6MB h = full per-XCD
// replication via capacity misses (h >> 4MB L2). Fix: FEATURE-chunked layout
// h[8][N][8]: chunk g = 3.2MB slab, resident in XCD g's L2 (blockIdx&7 ~ XCD).
// Wave = 8 rows x 8 feats; lane-local accumulate, no shfl in hot loop; ev
// streamed with NT loads, hout/accc NT so the slab stays resident.

__device__ __forceinline__ float waveReduceSum(float v) {
  #pragma unroll
  for (int m = 32; m > 0; m >>= 1) v += __shfl_xor(v, m, 64);
  return v;
}

__device__ __forceinline__ void ld_edge_nt(const int2* p, int& c, float& v) {
  unsigned long long u =
      __builtin_nontemporal_load((const unsigned long long*)p);
  c = (int)(u & 0xffffffffull);
  v = __int_as_float((int)(u >> 32));
}

// logmap0 -> chunk-major t[8][n][8]: t[f>>3][row][f&7]
__global__ __launch_bounds__(256) void k_logmap0(const float* __restrict__ x,
                                                 float* __restrict__ t, int n) {
  int wid = (blockIdx.x * blockDim.x + threadIdx.x) >> 6;
  int lane = threadIdx.x & 63;
  if (wid >= n) return;
  const float* row = x + (size_t)wid * 65;
  float x0 = row[0];
  float y = row[1 + lane];
  float ss = waveReduceSum(y * y);
  float nrm = fmaxf(sqrtf(ss), 1e-15f);
  float theta = fmaxf(x0, 1.0f + 1e-7f);
  float val = acoshf(theta) * (y / nrm);
  t[(size_t)(lane >> 3) * n * 8 + (size_t)wid * 8 + (lane & 7)] = val;
}

__global__ void k_hist(const int* __restrict__ rows, int* __restrict__ cnt, int e) {
  int i = blockIdx.x * blockDim.x + threadIdx.x;
  int stride = gridDim.x * blockDim.x;
  for (; i < e; i += stride) atomicAdd(&cnt[rows[i]], 1);
}

// ---- 3-phase multi-block exclusive scan over cnt[0..n) ----
__global__ __launch_bounds__(1024) void k_scan1(const int* __restrict__ cnt,
                                                int* __restrict__ off,
                                                int* __restrict__ bsum, int n) {
  __shared__ int sh[1024];
  int i = blockIdx.x * 1024 + threadIdx.x;
  int v = (i < n) ? cnt[i] : 0;
  sh[threadIdx.x] = v;
  __syncthreads();
  #pragma unroll
  for (int d = 1; d < 1024; d <<= 1) {
    int t = (threadIdx.x >= d) ? sh[threadIdx.x - d] : 0;
    __syncthreads();
    sh[threadIdx.x] += t;
    __syncthreads();
  }
  if (i < n) off[i] = sh[threadIdx.x] - v;
  if (threadIdx.x == 1023) bsum[blockIdx.x] = sh[1023];
}

__global__ __launch_bounds__(1024) void k_scan2(int* __restrict__ bsum, int nb) {
  __shared__ int sh[1024];
  int v = (threadIdx.x < nb) ? bsum[threadIdx.x] : 0;
  sh[threadIdx.x] = v;
  __syncthreads();
  #pragma unroll
  for (int d = 1; d < 1024; d <<= 1) {
    int t = (threadIdx.x >= d) ? sh[threadIdx.x - d] : 0;
    __syncthreads();
    sh[threadIdx.x] += t;
    __syncthreads();
  }
  if (threadIdx.x < nb) bsum[threadIdx.x] = sh[threadIdx.x] - v;
}

__global__ __launch_bounds__(1024) void k_scan3(int* __restrict__ off,
                                                const int* __restrict__ bsum,
                                                int* __restrict__ cursor,
                                                int n, int e) {
  int i = blockIdx.x * 1024 + threadIdx.x;
  if (i < n) {
    int o = off[i] + bsum[blockIdx.x];
    off[i] = o;
    cursor[i] = o;
  }
  if (i == 0) off[n] = e;
}

// XCD-partitioned scatter (r7, kept): group g=blockIdx&7 owns destination rows
// [g*step,(g+1)*step) so each CSR region is written by one XCD -> no
// cross-XCD partial-line writeback amplification.
__global__ __launch_bounds__(256) void k_scatter(const int* __restrict__ rows,
                                                 const int* __restrict__ cols,
                                                 const float* __restrict__ vals,
                                                 int* __restrict__ cursor,
                                                 int2* __restrict__ ev,
                                                 int e, int step) {
  int g = blockIdx.x & 7;
  int k = blockIdx.x >> 3;
  int tid = k * blockDim.x + threadIdx.x;
  int nthr = (gridDim.x >> 3) * blockDim.x;
  int rlo = g * step, rhi = rlo + step;
  for (int i = tid; i < e; i += nthr) {
    int r = rows[i];
    if (r >= rlo && r < rhi) {
      int p = atomicAdd(&cursor[r], 1);
      ev[p] = make_int2(cols[i], __float_as_int(vals[i]));
    }
  }
}

// Feature-chunked SpMM. Block -> chunk g = blockIdx&7 (XCD residue under
// default round-robin mapping; perf-only assumption). 4 waves/block, wave =
// 8 rows x 8 feats: lane (r8=lane>>3, f=lane&7) walks row r8's edge bucket.
// 8 lanes share each edge load (HW broadcast); gather hits the L2-resident
// 3.2MB slab hin[g]; stores are 256B coalesced per wave, NT to avoid
// evicting the slab.
__global__ __launch_bounds__(256) void k_spmm(const int* __restrict__ off,
                                              const int2* __restrict__ ev,
                                              const float* __restrict__ hin,
                                              float* __restrict__ hout,
                                              float* __restrict__ accc,
                                              int n, int first, int last) {
  int wid = threadIdx.x >> 6;
  int lane = threadIdx.x & 63;
  int g = blockIdx.x & 7;
  int r = ((blockIdx.x >> 3) * 4 + wid) * 8 + (lane >> 3);
  int f = lane & 7;
  const float* __restrict__ hg = hin + (size_t)g * n * 8;
  int s = 0, e = 0;
  if (r < n) { s = off[r]; e = off[r + 1]; }
  float a = 0.f;
  #pragma unroll 4
  for (int k = s; k < e; ++k) {
    int c; float v;
    ld_edge_nt(&ev[k], c, v);
    a += v * hg[(size_t)c * 8 + f];
  }
  if (r < n) {
    size_t o = (size_t)g * n * 8 + (size_t)r * 8 + f;
    if (!last) __builtin_nontemporal_store(a, &hout[o]);
    if (first) {
      __builtin_nontemporal_store(a, &accc[o]);
    } else {
      float prev = __builtin_nontemporal_load(&accc[o]);
      __builtin_nontemporal_store(prev + a, &accc[o]);
    }
  }
}

// accc (chunk-major) -> d_out rows: [sqrt(max(1+||tail||^2,1e-7)), tail],
// tail = sinh(nrm)/nrm * acc, nrm = max(||acc||, 1e-15)
__global__ __launch_bounds__(256) void k_final(const float* __restrict__ accc,
                                               float* __restrict__ out, int n) {
  int wid = (blockIdx.x * blockDim.x + threadIdx.x) >> 6;
  int lane = threadIdx.x & 63;
  if (wid >= n) return;
  float a = accc[(size_t)(lane >> 3) * n * 8 + (size_t)wid * 8 + (lane & 7)];
  float ss = waveReduceSum(a * a);
  float nrm = fmaxf(sqrtf(ss), 1e-15f);
  float sh = sinhf(nrm) / nrm;
  float tl = sh * a;
  float ss2 = waveReduceSum(tl * tl);
  float first = sqrtf(fmaxf(1.0f + ss2, 1e-7f));
  float* row = out + (size_t)wid * 65;
  row[1 + lane] = tl;
  if (lane == 0) row[0] = first;
}

extern "C" void kernel_launch(void* const* d_in, const int* in_sizes, int n_in,
                              void* d_out, int out_size, void* d_ws, size_t ws_size,
                              hipStream_t stream) {
  const float* x = (const float*)d_in[0];
  const int* rows = (const int*)d_in[1];
  const int* cols = (const int*)d_in[2];
  const float* vals = (const float*)d_in[3];
  float* out = (float*)d_out;
  int n = in_sizes[0] / 65;
  int e = in_sizes[1];

  // workspace layout (~90.4 MB total)
  char* w = (char*)d_ws;
  auto alloc = [&](size_t bytes) {
    void* p = (void*)w;
    w += (bytes + 255) & ~(size_t)255;
    return p;
  };
  int* cnt   = (int*)alloc((size_t)n * 4);           // histogram -> cursor
  int* off   = (int*)alloc(((size_t)n + 1) * 4);     // CSR row offsets
  int* bsum  = (int*)alloc(1024 * 4);                // scan block sums
  int2* ev   = (int2*)alloc((size_t)e * 8);          // packed bucketed edges
  float* h0c = (float*)alloc((size_t)n * 64 * 4);    // chunk-major ping
  float* h1c = (float*)alloc((size_t)n * 64 * 4);    // chunk-major pong
  float* acc = (float*)alloc((size_t)n * 64 * 4);    // chunk-major 3-hop acc

  hipMemsetAsync(cnt, 0, (size_t)n * 4, stream);

  int nwb  = (n + 3) / 4;          // 4 waves (1 row each) per 256-thread block
  int nsb  = (n + 1023) / 1024;    // scan blocks
  int step = (n + 7) / 8;          // rows per XCD partition (scatter)
  int nrg  = (n + 7) / 8;          // row-groups of 8 rows (spmm)
  int bpc  = (nrg + 3) / 4;        // blocks per chunk (4 row-groups/block)
  int sgrid = bpc * 8;             // x8 chunks

  k_logmap0<<<nwb, 256, 0, stream>>>(x, h0c, n);
  k_hist<<<2048, 256, 0, stream>>>(rows, cnt, e);
  k_scan1<<<nsb, 1024, 0, stream>>>(cnt, off, bsum, n);
  k_scan2<<<1, 1024, 0, stream>>>(bsum, nsb);
  k_scan3<<<nsb, 1024, 0, stream>>>(off, bsum, cnt, n, e);
  k_scatter<<<2048, 256, 0, stream>>>(rows, cols, vals, cnt, ev, e, step);

  k_spmm<<<sgrid, 256, 0, stream>>>(off, ev, h0c, h1c, acc, n, 1, 0);
  k_spmm<<<sgrid, 256, 0, stream>>>(off, ev, h1c, h0c, acc, n, 0, 0);
  k_spmm<<<sgrid, 256, 0, stream>>>(off, ev, h0c, h1c, acc, n, 0, 1);

  k_final<<<nwb, 256, 0, stream>>>(acc, out, n);
}